// Round 1
// baseline (6900.049 us; speedup 1.0000x reference)
//
#include <hip/hip_runtime.h>

// 2-layer tanh RNN, B=64 T=512 H=512, f32 in/out.
// Weights split hi+lo bf16 (w=hi+lo) -> 2 MFMA passes/operand, f32-grade acc.
// 64 WGs x 256 thr; blocks 0..31 layer 0, 32..63 layer 1 (concat-K fused,
// one step behind). R8: flagless TAG-IN-DATA sync — each 8B h-packet carries
// a step-parity bit in the mantissa LSB of its first bf16; consumers poll the
// ring data directly (reload-all retry = 1 RTT/iter, traffic spread over the
// whole ring instead of 64 flag lines). Depth-8 h1 ring decouples the two
// layers (layer1 WAR protected by a lazy progress back-channel, refreshed at
// step top / checked before store). No per-step barriers, no release fences,
// no store-ack drains. Prior flag design measured 8.94us/step with all
// utilization counters <1% (pure sync latency).

#define HD 512
#define BATCH 64
#define SEQ 512
#define NVOCAB 25
#define OUTD 1000
#define NWG 32
#define BH (BATCH * HD)   // 32768 u16 per ring slot
#define BHQ (BH / 4)      // 8192 u64 per ring slot
#define D1 8              // h1 ring depth (layer0 may run <=7 steps ahead)
#define LOGD1 3
#define D2 2              // h2 ring depth (self-synchronized, provably safe)
#define LOGD2 1
#define PSTRIDE 16        // ints per progress slot (64B line, one writer each)
#define IS64_OFF 2048
#define HDR_INTS 4096
#define GUARD_MAX (1L << 21)  // total spin budget per thread (fail-fast, no hang)

typedef unsigned short u16;
typedef unsigned int u32;
typedef unsigned long long u64;
typedef __attribute__((ext_vector_type(8))) short short8;  // 8 bf16
typedef __attribute__((ext_vector_type(4))) float f32x4;

union FragU { u16 h[8]; u64 q[2]; short8 v; };
union SharedU {
    u16 w1[2][16][4][16][8];   // layer1: Wih1 hi/lo frags (32 KB)
    float e0[HD * NVOCAB];     // layer0: Wih0 embedding table (50 KB)
};

__device__ __forceinline__ float bf2f(u16 v) {
    union { u32 u; float f; } c; c.u = ((u32)v) << 16; return c.f;
}
__device__ __forceinline__ u16 f2bf(float f) {
    union { float f; u32 u; } c; c.f = f;
    return (u16)((c.u + 0x7FFFu + ((c.u >> 16) & 1u)) >> 16);  // RNE
}
__device__ __forceinline__ u64 ld64(const u64* p) {
    return __hip_atomic_load((u64*)p, __ATOMIC_RELAXED, __HIP_MEMORY_SCOPE_AGENT);
}
__device__ __forceinline__ void st64(u64* p, u64 v) {
    __hip_atomic_store(p, v, __ATOMIC_RELAXED, __HIP_MEMORY_SCOPE_AGENT);
}
__device__ __forceinline__ int ld32(const int* p) {
    return __hip_atomic_load((int*)p, __ATOMIC_RELAXED, __HIP_MEMORY_SCOPE_AGENT);
}
__device__ __forceinline__ u64 pack_tag(const u16 hv[4], u32 tag) {
    return ((u64)(((u32)hv[0] & 0xFFFEu) | tag))
         | ((u64)hv[1] << 16) | ((u64)hv[2] << 32) | ((u64)hv[3] << 48);
}

// hdr ints: prog[128 slots * 16] in [0,2048) | is64 @ [2048].
// Rings: slot 0 = zeros (valid h[0], tag 0); slots >=1 = u64 1 (tag 1 =
// mismatch marker for first write, whose tag is 0).
__global__ void init_kernel(int* hdr, u64* h1, u64* h2, const int* x32) {
    long i = (long)blockIdx.x * 256 + threadIdx.x;
    if (i < HDR_INTS) {
        if (i == IS64_OFF) {  // probe x int width: int64 LE => odd words all 0
            int all0 = 1;
            for (int j = 0; j < 64; ++j) if (x32[2 * j + 1] != 0) all0 = 0;
            hdr[i] = all0;
        } else hdr[i] = 0;
    } else {
        long r = i - HDR_INTS;
        if (r < (long)D1 * BHQ) h1[r] = (r < BHQ) ? 0ull : 1ull;
        else {
            long s = r - (long)D1 * BHQ;
            if (s < (long)D2 * BHQ) h2[s] = (s < BHQ) ? 0ull : 1ull;
        }
    }
}

__global__ __launch_bounds__(256, 1) void rnn_fused(
    const float* __restrict__ Whh0, const float* __restrict__ Wih0,
    const int* __restrict__ x,
    const float* __restrict__ bih0, const float* __restrict__ bhh0,
    const float* __restrict__ Whh1, const float* __restrict__ Wih1,
    const float* __restrict__ bih1, const float* __restrict__ bhh1,
    u64* h1ring, u64* h2ring, float* h2final, int* hdr)
{
    int* prog = hdr;  // layer1 wave (g,c) publishes "h1[s] consumed" at slot g*4+c
    const int tid  = threadIdx.x;
    const int wave = tid >> 6;
    const int lane = tid & 63;
    const int quad = lane >> 4;
    const int l16  = lane & 15;
    const int layer = blockIdx.x >> 5;          // 0 or 1
    const int g = blockIdx.x & 31;
    const int rowbase = g * 16;                 // 32 WGs x 16 rows = 512
    const int arow = rowbase + l16;             // A row (m = lane&15)
    const int row0 = rowbase + quad * 4;        // C/D rows: quad*4 + reg
    const int col  = wave * 16 + l16;           // C/D col (batch)
    const int myprog = (g * 4 + wave) * PSTRIDE;

    __shared__ SharedU sh;

    // Whh split hi/lo bf16, register-resident: A[m=lane&15][k=quad*8+j].
    const float* Wself = layer ? Whh1 : Whh0;
    short8 Ah[16], Al[16];
    #pragma unroll
    for (int kc = 0; kc < 16; ++kc) {
        FragU th, tl;
        #pragma unroll
        for (int j = 0; j < 8; ++j) {
            float w = Wself[arow * HD + kc * 32 + quad * 8 + j];
            u16 hi = f2bf(w);
            th.h[j] = hi;
            tl.h[j] = f2bf(w - bf2f(hi));
        }
        Ah[kc] = th.v; Al[kc] = tl.v;
    }
    if (layer == 0) {
        for (int i = tid; i < HD * NVOCAB; i += 256) sh.e0[i] = Wih0[i];
    } else if (wave == 0) {  // all 4 waves share the same A rows
        #pragma unroll
        for (int kc = 0; kc < 16; ++kc) {
            FragU th, tl;
            #pragma unroll
            for (int j = 0; j < 8; ++j) {
                float w = Wih1[arow * HD + kc * 32 + quad * 8 + j];
                u16 hi = f2bf(w);
                th.h[j] = hi;
                tl.h[j] = f2bf(w - bf2f(hi));
            }
            *(short8*)&sh.w1[0][kc][quad][l16][0] = th.v;
            *(short8*)&sh.w1[1][kc][quad][l16][0] = tl.v;
        }
    }
    const float* bA = layer ? bih1 : bih0;
    const float* bB = layer ? bhh1 : bhh0;
    float bsum[4];
    #pragma unroll
    for (int i = 0; i < 4; ++i) bsum[i] = bA[row0 + i] + bB[row0 + i];
    const int is64 = hdr[IS64_OFF];
    __syncthreads();  // covers LDS init; NO barriers inside the step loop

    long guard = 0;
    int pv = 0;  // cached layer1 progress (lanes 0..31), monotone

    for (int t = 0; t < SEQ; ++t) {
        if (layer == 0) {
            // x gather issued first (overlaps the data poll)
            int xi = is64 ? (int)((const long long*)x)[col * SEQ + t]
                          : x[col * SEQ + t];
            // WAR back-channel: refresh early (non-blocking), check before store.
            const int need = t + 1 - D1;  // layer1 must have consumed h1[need]
            if (need > 0) {
                bool stale = (lane < 32) && (pv < need);
                if (__ballot(stale) != 0ULL && lane < 32)
                    pv = ld32(prog + (lane * 4 + wave) * PSTRIDE);
            }
            // ---- data poll: h1[t], tag = parity of t>>LOGD1 ----
            const int sl = t & (D1 - 1);
            const u32 ex = (u32)((t >> LOGD1) & 1);
            const u64* pb = h1ring + (size_t)sl * BHQ + col * 128 + quad * 2;
            u64 q[32];
            for (;;) {
                #pragma unroll
                for (int kc = 0; kc < 16; ++kc) {
                    q[2 * kc]     = ld64(pb + kc * 8);
                    q[2 * kc + 1] = ld64(pb + kc * 8 + 1);
                }
                u32 bad = 0;
                #pragma unroll
                for (int j = 0; j < 32; ++j) bad |= ((u32)q[j] ^ ex) & 1u;
                if (__ballot(bad != 0) == 0ULL) break;
                if (++guard > GUARD_MAX) break;
            }
            float wx[4];
            #pragma unroll
            for (int i = 0; i < 4; ++i) wx[i] = sh.e0[(row0 + i) * NVOCAB + xi];
            // two independent acc chains (hi/lo) for MFMA ILP
            f32x4 aH = {0.f, 0.f, 0.f, 0.f}, aL = {0.f, 0.f, 0.f, 0.f};
            #pragma unroll
            for (int kc = 0; kc < 16; ++kc) {
                FragU f; f.q[0] = q[2 * kc]; f.q[1] = q[2 * kc + 1];
                aH = __builtin_amdgcn_mfma_f32_16x16x32_bf16(Ah[kc], f.v, aH, 0, 0, 0);
                aL = __builtin_amdgcn_mfma_f32_16x16x32_bf16(Al[kc], f.v, aL, 0, 0, 0);
            }
            float hf[4]; u16 hv[4];
            #pragma unroll
            for (int i = 0; i < 4; ++i) {
                float pre = aH[i] + aL[i] + bsum[i] + wx[i];
                hf[i] = tanhf(pre); hv[i] = f2bf(hf[i]);
            }
            // blocking WAR check (normally satisfied by the early refresh)
            if (need > 0) {
                while (__ballot((lane < 32) && (pv < need)) != 0ULL) {
                    if (lane < 32) pv = ld32(prog + (lane * 4 + wave) * PSTRIDE);
                    if (++guard > GUARD_MAX) break;
                }
            }
            const int wsl = (t + 1) & (D1 - 1);
            const u32 wtg = (u32)(((t + 1) >> LOGD1) & 1);
            st64(h1ring + (size_t)wsl * BHQ + col * 128 + (row0 >> 2),
                 pack_tag(hv, wtg));
        } else {
            // ---- data poll: h2[t] and h1[t+1] in one retry loop ----
            const int s2 = t & (D2 - 1);
            const u32 e2 = (u32)((t >> LOGD2) & 1);
            const int s1 = (t + 1) & (D1 - 1);
            const u32 e1 = (u32)(((t + 1) >> LOGD1) & 1);
            const u64* pb2 = h2ring + (size_t)s2 * BHQ + col * 128 + quad * 2;
            const u64* pb1 = h1ring + (size_t)s1 * BHQ + col * 128 + quad * 2;
            u64 q2[32], q1[32];
            for (;;) {
                #pragma unroll
                for (int kc = 0; kc < 16; ++kc) {
                    q2[2 * kc]     = ld64(pb2 + kc * 8);
                    q2[2 * kc + 1] = ld64(pb2 + kc * 8 + 1);
                    q1[2 * kc]     = ld64(pb1 + kc * 8);
                    q1[2 * kc + 1] = ld64(pb1 + kc * 8 + 1);
                }
                u32 bad = 0;
                #pragma unroll
                for (int j = 0; j < 32; ++j) {
                    bad |= ((u32)q2[j] ^ e2) & 1u;
                    bad |= ((u32)q1[j] ^ e1) & 1u;
                }
                if (__ballot(bad != 0) == 0ULL) break;
                if (++guard > GUARD_MAX) break;
            }
            // publish "h1[t+1] consumed" (ordered after loads via data dep)
            if (lane == 0) {
                int pubv = t + 1;
                u32 dep = (u32)q1[0];
                asm volatile("" : "+v"(pubv) : "v"(dep));
                __hip_atomic_store(prog + myprog, pubv,
                                   __ATOMIC_RELAXED, __HIP_MEMORY_SCOPE_AGENT);
            }
            // four independent acc chains for MFMA ILP
            f32x4 aSH = {0.f, 0.f, 0.f, 0.f}, aSL = aSH, aIH = aSH, aIL = aSH;
            #pragma unroll
            for (int kc = 0; kc < 16; ++kc) {
                FragU f2; f2.q[0] = q2[2 * kc]; f2.q[1] = q2[2 * kc + 1];
                FragU f1; f1.q[0] = q1[2 * kc]; f1.q[1] = q1[2 * kc + 1];
                aSH = __builtin_amdgcn_mfma_f32_16x16x32_bf16(Ah[kc], f2.v, aSH, 0, 0, 0);
                aSL = __builtin_amdgcn_mfma_f32_16x16x32_bf16(Al[kc], f2.v, aSL, 0, 0, 0);
                short8 w1h = *(short8*)&sh.w1[0][kc][quad][l16][0];
                short8 w1l = *(short8*)&sh.w1[1][kc][quad][l16][0];
                aIH = __builtin_amdgcn_mfma_f32_16x16x32_bf16(w1h, f1.v, aIH, 0, 0, 0);
                aIL = __builtin_amdgcn_mfma_f32_16x16x32_bf16(w1l, f1.v, aIL, 0, 0, 0);
            }
            float hf[4]; u16 hv[4];
            #pragma unroll
            for (int i = 0; i < 4; ++i) {
                float pre = aSH[i] + aSL[i] + aIH[i] + aIL[i] + bsum[i];
                hf[i] = tanhf(pre); hv[i] = f2bf(hf[i]);
            }
            const int wsl = (t + 1) & (D2 - 1);
            const u32 wtg = (u32)(((t + 1) >> LOGD2) & 1);
            st64(h2ring + (size_t)wsl * BHQ + col * 128 + (row0 >> 2),
                 pack_tag(hv, wtg));
            if (t == SEQ - 1)
                *(f32x4*)(h2final + col * HD + row0) = *(f32x4*)hf;  // exact f32
        }
    }
}

__global__ __launch_bounds__(256) void out_kernel(
    const float* __restrict__ h2last, const float* __restrict__ Wout,
    const float* __restrict__ bout, float* __restrict__ out)
{
    int o = blockIdx.x * 256 + threadIdx.x;
    int b = blockIdx.y;
    if (o >= OUTD) return;
    const float* hrow = h2last + b * HD;
    const float* wrow = Wout + o * HD;
    float acc = 0.f;
    for (int k = 0; k < HD; k += 4) {
        float4 hv = *(const float4*)(hrow + k);
        float4 wv = *(const float4*)(wrow + k);
        acc += hv.x * wv.x + hv.y * wv.y + hv.z * wv.z + hv.w * wv.w;
    }
    out[b * OUTD + o] = acc + bout[o];
}

extern "C" void kernel_launch(void* const* d_in, const int* in_sizes, int n_in,
                              void* d_out, int out_size, void* d_ws, size_t ws_size,
                              hipStream_t stream) {
    const int*   x     = (const int*)d_in[0];
    const float* W_ih0 = (const float*)d_in[1];
    const float* W_hh0 = (const float*)d_in[2];
    const float* b_ih0 = (const float*)d_in[3];
    const float* b_hh0 = (const float*)d_in[4];
    const float* W_ih1 = (const float*)d_in[5];
    const float* W_hh1 = (const float*)d_in[6];
    const float* b_ih1 = (const float*)d_in[7];
    const float* b_hh1 = (const float*)d_in[8];
    const float* W_out = (const float*)d_in[9];
    const float* b_out = (const float*)d_in[10];

    // ws: hdr 16KB | h1ring D1*64KB (512KB) | h2ring D2*64KB (128KB) | h2final 128KB
    const size_t needed = (size_t)HDR_INTS * 4 + (size_t)D1 * BHQ * 8
                        + (size_t)D2 * BHQ * 8 + (size_t)BH * 4;  // 802816 B
    if (ws_size < needed) return;  // signature: absmax=0.149 non-NaN => ws short

    int* hdr = (int*)d_ws;
    u64* h1ring = (u64*)((char*)d_ws + (size_t)HDR_INTS * 4);
    u64* h2ring = h1ring + (size_t)D1 * BHQ;
    float* h2final = (float*)(h2ring + (size_t)D2 * BHQ);

    const long ninit = HDR_INTS + (long)D1 * BHQ + (long)D2 * BHQ;  // 86016
    init_kernel<<<(int)((ninit + 255) / 256), 256, 0, stream>>>(hdr, h1ring, h2ring, x);
    rnn_fused<<<2 * NWG, 256, 0, stream>>>(W_hh0, W_ih0, x, b_ih0, b_hh0,
                                           W_hh1, W_ih1, b_ih1, b_hh1,
                                           h1ring, h2ring, h2final, hdr);
    out_kernel<<<dim3(4, BATCH), 256, 0, stream>>>(h2final, W_out, b_out, (float*)d_out);
}

// Round 2
// 4665.630 us; speedup vs baseline: 1.4789x; 1.4789x over previous
//
#include <hip/hip_runtime.h>

// 2-layer tanh RNN, B=64 T=512 H=512, f32 in/out.
// Weights split hi+lo bf16 (w=hi+lo) -> 2 MFMA passes/operand, f32-grade acc.
// 64 WGs x 256 thr; blocks 0..31 layer 0, 32..63 layer 1 (concat-K fused,
// one step behind). Free-running waves, no per-step barriers/fences.
// R9: REP-GATED tag-in-data sync. Producer threads store one tagged 8B packet
// (step-parity bit in mantissa LSB of first bf16) fire-and-forget. Consumers
// first poll one REPRESENTATIVE packet per producer wave (32 lanes x 8B --
// as cheap as R7's flag poll), then run the full self-validating data sweep
// (usually 1 iteration). Fixes R8's regression (13.5us/step): sweeping
// 64-128KB as the polling primitive flooded TCC/IF$ (FETCH 450MB, RTTs
// inflated). Also reverts Wih0 embed gather to global L1 reads (R8's LDS
// stride-25 gather: 5.1e7 bank-conflict cycles). Depth-8 h1 ring + lazy
// progress back-channel retained (WAR safety; layer decoupling itself is
// neutral -- each layer's self-loop is the critical path).
// History: R7 flags+barriers = 8.94us/step; R8 sweep-poll = 13.5us/step.

#define HD 512
#define BATCH 64
#define SEQ 512
#define NVOCAB 25
#define OUTD 1000
#define NWG 32
#define BH (BATCH * HD)   // 32768 u16 per ring slot
#define BHQ (BH / 4)      // 8192 u64 per ring slot
#define D1 8              // h1 ring depth (layer0 may run <=7 steps ahead)
#define LOGD1 3
#define D2 2              // h2 ring depth (self-synchronized, provably safe)
#define LOGD2 1
#define PSTRIDE 16        // ints per progress slot (64B line, one writer each)
#define IS64_OFF 2048
#define HDR_INTS 4096
#define GUARD_MAX (1L << 21)  // total spin budget per thread (fail-fast, no hang)

typedef unsigned short u16;
typedef unsigned int u32;
typedef unsigned long long u64;
typedef __attribute__((ext_vector_type(8))) short short8;  // 8 bf16
typedef __attribute__((ext_vector_type(4))) float f32x4;

union FragU { u16 h[8]; u64 q[2]; short8 v; };

__device__ __forceinline__ float bf2f(u16 v) {
    union { u32 u; float f; } c; c.u = ((u32)v) << 16; return c.f;
}
__device__ __forceinline__ u16 f2bf(float f) {
    union { float f; u32 u; } c; c.f = f;
    return (u16)((c.u + 0x7FFFu + ((c.u >> 16) & 1u)) >> 16);  // RNE
}
__device__ __forceinline__ u64 ld64(const u64* p) {
    return __hip_atomic_load((u64*)p, __ATOMIC_RELAXED, __HIP_MEMORY_SCOPE_AGENT);
}
__device__ __forceinline__ void st64(u64* p, u64 v) {
    __hip_atomic_store(p, v, __ATOMIC_RELAXED, __HIP_MEMORY_SCOPE_AGENT);
}
__device__ __forceinline__ int ld32(const int* p) {
    return __hip_atomic_load((int*)p, __ATOMIC_RELAXED, __HIP_MEMORY_SCOPE_AGENT);
}
__device__ __forceinline__ u64 pack_tag(const u16 hv[4], u32 tag) {
    return ((u64)(((u32)hv[0] & 0xFFFEu) | tag))
         | ((u64)hv[1] << 16) | ((u64)hv[2] << 32) | ((u64)hv[3] << 48);
}

// hdr ints: prog[128 slots * 16] in [0,2048) | is64 @ [2048].
// Rings: slot 0 = zeros (valid h[0], tag 0); slots >=1 = u64 1 (tag 1 =
// mismatch marker for first write, whose tag is 0).
__global__ void init_kernel(int* hdr, u64* h1, u64* h2, const int* x32) {
    long i = (long)blockIdx.x * 256 + threadIdx.x;
    if (i < HDR_INTS) {
        if (i == IS64_OFF) {  // probe x int width: int64 LE => odd words all 0
            int all0 = 1;
            for (int j = 0; j < 64; ++j) if (x32[2 * j + 1] != 0) all0 = 0;
            hdr[i] = all0;
        } else hdr[i] = 0;
    } else {
        long r = i - HDR_INTS;
        if (r < (long)D1 * BHQ) h1[r] = (r < BHQ) ? 0ull : 1ull;
        else {
            long s = r - (long)D1 * BHQ;
            if (s < (long)D2 * BHQ) h2[s] = (s < BHQ) ? 0ull : 1ull;
        }
    }
}

__global__ __launch_bounds__(256, 1) void rnn_fused(
    const float* __restrict__ Whh0, const float* __restrict__ Wih0,
    const int* __restrict__ x,
    const float* __restrict__ bih0, const float* __restrict__ bhh0,
    const float* __restrict__ Whh1, const float* __restrict__ Wih1,
    const float* __restrict__ bih1, const float* __restrict__ bhh1,
    u64* h1ring, u64* h2ring, float* h2final, int* hdr)
{
    int* prog = hdr;  // layer1 wave (g,c) publishes "h1[s] consumed" at slot g*4+c
    const int tid  = threadIdx.x;
    const int wave = tid >> 6;
    const int lane = tid & 63;
    const int quad = lane >> 4;
    const int l16  = lane & 15;
    const int layer = blockIdx.x >> 5;          // 0 or 1
    const int g = blockIdx.x & 31;
    const int rowbase = g * 16;                 // 32 WGs x 16 rows = 512
    const int arow = rowbase + l16;             // A row (m = lane&15)
    const int row0 = rowbase + quad * 4;        // C/D rows: quad*4 + reg
    const int col  = wave * 16 + l16;           // C/D col (batch)
    const int myprog = (g * 4 + wave) * PSTRIDE;
    // representative packet offset for producer WG pg, within my col-plane:
    // col = wave*16 + (pg&15), u64 idx = 4*pg + (pg&3)  (rows 16pg+4(pg&3)..+4)
    const int pg = lane & 31;
    const size_t repoff = (size_t)(wave * 16 + (pg & 15)) * 128 + 4 * pg + (pg & 3);

    __shared__ u16 ldsW[2][16][4][16][8];       // layer1: Wih1 hi/lo frags, 32 KB

    // Whh split hi/lo bf16, register-resident: A[m=lane&15][k=quad*8+j].
    const float* Wself = layer ? Whh1 : Whh0;
    short8 Ah[16], Al[16];
    #pragma unroll
    for (int kc = 0; kc < 16; ++kc) {
        FragU th, tl;
        #pragma unroll
        for (int j = 0; j < 8; ++j) {
            float w = Wself[arow * HD + kc * 32 + quad * 8 + j];
            u16 hi = f2bf(w);
            th.h[j] = hi;
            tl.h[j] = f2bf(w - bf2f(hi));
        }
        Ah[kc] = th.v; Al[kc] = tl.v;
    }
    if (layer && wave == 0) {  // all 4 waves share the same A rows
        #pragma unroll
        for (int kc = 0; kc < 16; ++kc) {
            FragU th, tl;
            #pragma unroll
            for (int j = 0; j < 8; ++j) {
                float w = Wih1[arow * HD + kc * 32 + quad * 8 + j];
                u16 hi = f2bf(w);
                th.h[j] = hi;
                tl.h[j] = f2bf(w - bf2f(hi));
            }
            *(short8*)&ldsW[0][kc][quad][l16][0] = th.v;
            *(short8*)&ldsW[1][kc][quad][l16][0] = tl.v;
        }
    }
    const float* bA = layer ? bih1 : bih0;
    const float* bB = layer ? bhh1 : bhh0;
    float bsum[4];
    #pragma unroll
    for (int i = 0; i < 4; ++i) bsum[i] = bA[row0 + i] + bB[row0 + i];
    const int is64 = hdr[IS64_OFF];
    __syncthreads();  // covers LDS init; NO barriers inside the step loop

    long guard = 0;
    int pv = 0;  // cached layer1 progress (lanes 0..31), monotone

    for (int t = 0; t < SEQ; ++t) {
        if (layer == 0) {
            // x gather + embed row prefetch (global, L1-resident 50KB table);
            // issued before the poll so it's in flight during the wait.
            int xi = is64 ? (int)((const long long*)x)[col * SEQ + t]
                          : x[col * SEQ + t];
            float wx[4];
            #pragma unroll
            for (int i = 0; i < 4; ++i) wx[i] = Wih0[(row0 + i) * NVOCAB + xi];
            // WAR back-channel: refresh early (non-blocking), check before store.
            const int need = t + 1 - D1;  // layer1 must have consumed h1[need]
            if (need > 0) {
                bool stale = (lane < 32) && (pv < need);
                if (__ballot(stale) != 0ULL && lane < 32)
                    pv = ld32(prog + (lane * 4 + wave) * PSTRIDE);
            }
            const int sl = t & (D1 - 1);
            const u32 ex = (u32)((t >> LOGD1) & 1);
            const u64* sbase = h1ring + (size_t)sl * BHQ;
            // ---- rep poll: one packet per producer WG (8B/lane/iter) ----
            {
                const u64* rep = sbase + repoff;
                for (;;) {
                    u32 bad = (((u32)ld64(rep)) ^ ex) & 1u;
                    if (__ballot(bad != 0) == 0ULL) break;
                    if (++guard > GUARD_MAX) break;
                    __builtin_amdgcn_s_sleep(1);
                }
            }
            // ---- data sweep (self-validating tags; usually 1 iteration) ----
            const u64* pb = sbase + (size_t)col * 128 + quad * 2;
            u64 q[32];
            for (;;) {
                #pragma unroll
                for (int kc = 0; kc < 16; ++kc) {
                    q[2 * kc]     = ld64(pb + kc * 8);
                    q[2 * kc + 1] = ld64(pb + kc * 8 + 1);
                }
                u32 bad = 0;
                #pragma unroll
                for (int j = 0; j < 32; ++j) bad |= ((u32)q[j] ^ ex) & 1u;
                if (__ballot(bad != 0) == 0ULL) break;
                if (++guard > GUARD_MAX) break;
            }
            // two independent acc chains (hi/lo) for MFMA ILP
            f32x4 aH = {0.f, 0.f, 0.f, 0.f}, aL = {0.f, 0.f, 0.f, 0.f};
            #pragma unroll
            for (int kc = 0; kc < 16; ++kc) {
                FragU f; f.q[0] = q[2 * kc]; f.q[1] = q[2 * kc + 1];
                aH = __builtin_amdgcn_mfma_f32_16x16x32_bf16(Ah[kc], f.v, aH, 0, 0, 0);
                aL = __builtin_amdgcn_mfma_f32_16x16x32_bf16(Al[kc], f.v, aL, 0, 0, 0);
            }
            float hf[4]; u16 hv[4];
            #pragma unroll
            for (int i = 0; i < 4; ++i) {
                float pre = aH[i] + aL[i] + bsum[i] + wx[i];
                hf[i] = tanhf(pre); hv[i] = f2bf(hf[i]);
            }
            // blocking WAR check (normally satisfied by the early refresh)
            if (need > 0) {
                while (__ballot((lane < 32) && (pv < need)) != 0ULL) {
                    if (lane < 32) pv = ld32(prog + (lane * 4 + wave) * PSTRIDE);
                    if (++guard > GUARD_MAX) break;
                }
            }
            const int wsl = (t + 1) & (D1 - 1);
            const u32 wtg = (u32)(((t + 1) >> LOGD1) & 1);
            st64(h1ring + (size_t)wsl * BHQ + col * 128 + (row0 >> 2),
                 pack_tag(hv, wtg));  // fire-and-forget; tag is the flag
        } else {
            const int s2 = t & (D2 - 1);
            const u32 e2 = (u32)((t >> LOGD2) & 1);
            const int s1 = (t + 1) & (D1 - 1);
            const u32 e1 = (u32)(((t + 1) >> LOGD1) & 1);
            const u64* b2 = h2ring + (size_t)s2 * BHQ;
            const u64* b1 = h1ring + (size_t)s1 * BHQ;
            // ---- rep poll: lanes 0-31 watch h2[t], lanes 32-63 watch h1[t+1] ----
            {
                const u64* rep = (lane < 32) ? (b2 + repoff) : (b1 + repoff);
                const u32 exr = (lane < 32) ? e2 : e1;
                for (;;) {
                    u32 bad = (((u32)ld64(rep)) ^ exr) & 1u;
                    if (__ballot(bad != 0) == 0ULL) break;
                    if (++guard > GUARD_MAX) break;
                    __builtin_amdgcn_s_sleep(1);
                }
            }
            // ---- combined data sweep ----
            const u64* pb2 = b2 + (size_t)col * 128 + quad * 2;
            const u64* pb1 = b1 + (size_t)col * 128 + quad * 2;
            u64 q2[32], q1[32];
            for (;;) {
                #pragma unroll
                for (int kc = 0; kc < 16; ++kc) {
                    q2[2 * kc]     = ld64(pb2 + kc * 8);
                    q2[2 * kc + 1] = ld64(pb2 + kc * 8 + 1);
                    q1[2 * kc]     = ld64(pb1 + kc * 8);
                    q1[2 * kc + 1] = ld64(pb1 + kc * 8 + 1);
                }
                u32 bad = 0;
                #pragma unroll
                for (int j = 0; j < 32; ++j) {
                    bad |= ((u32)q2[j] ^ e2) & 1u;
                    bad |= ((u32)q1[j] ^ e1) & 1u;
                }
                if (__ballot(bad != 0) == 0ULL) break;
                if (++guard > GUARD_MAX) break;
            }
            // publish "h1[t+1] consumed" (ordered after loads via data dep)
            if (lane == 0) {
                int pubv = t + 1;
                u32 dep = (u32)q1[0];
                asm volatile("" : "+v"(pubv) : "v"(dep));
                __hip_atomic_store(prog + myprog, pubv,
                                   __ATOMIC_RELAXED, __HIP_MEMORY_SCOPE_AGENT);
            }
            // four independent acc chains for MFMA ILP
            f32x4 aSH = {0.f, 0.f, 0.f, 0.f}, aSL = aSH, aIH = aSH, aIL = aSH;
            #pragma unroll
            for (int kc = 0; kc < 16; ++kc) {
                FragU f2; f2.q[0] = q2[2 * kc]; f2.q[1] = q2[2 * kc + 1];
                FragU f1; f1.q[0] = q1[2 * kc]; f1.q[1] = q1[2 * kc + 1];
                aSH = __builtin_amdgcn_mfma_f32_16x16x32_bf16(Ah[kc], f2.v, aSH, 0, 0, 0);
                aSL = __builtin_amdgcn_mfma_f32_16x16x32_bf16(Al[kc], f2.v, aSL, 0, 0, 0);
                short8 w1h = *(short8*)&ldsW[0][kc][quad][l16][0];
                short8 w1l = *(short8*)&ldsW[1][kc][quad][l16][0];
                aIH = __builtin_amdgcn_mfma_f32_16x16x32_bf16(w1h, f1.v, aIH, 0, 0, 0);
                aIL = __builtin_amdgcn_mfma_f32_16x16x32_bf16(w1l, f1.v, aIL, 0, 0, 0);
            }
            float hf[4]; u16 hv[4];
            #pragma unroll
            for (int i = 0; i < 4; ++i) {
                float pre = aSH[i] + aSL[i] + aIH[i] + aIL[i] + bsum[i];
                hf[i] = tanhf(pre); hv[i] = f2bf(hf[i]);
            }
            const int wsl = (t + 1) & (D2 - 1);
            const u32 wtg = (u32)(((t + 1) >> LOGD2) & 1);
            st64(h2ring + (size_t)wsl * BHQ + col * 128 + (row0 >> 2),
                 pack_tag(hv, wtg));
            if (t == SEQ - 1)
                *(f32x4*)(h2final + col * HD + row0) = *(f32x4*)hf;  // exact f32
        }
    }
}

__global__ __launch_bounds__(256) void out_kernel(
    const float* __restrict__ h2last, const float* __restrict__ Wout,
    const float* __restrict__ bout, float* __restrict__ out)
{
    int o = blockIdx.x * 256 + threadIdx.x;
    int b = blockIdx.y;
    if (o >= OUTD) return;
    const float* hrow = h2last + b * HD;
    const float* wrow = Wout + o * HD;
    float acc = 0.f;
    for (int k = 0; k < HD; k += 4) {
        float4 hv = *(const float4*)(hrow + k);
        float4 wv = *(const float4*)(wrow + k);
        acc += hv.x * wv.x + hv.y * wv.y + hv.z * wv.z + hv.w * wv.w;
    }
    out[b * OUTD + o] = acc + bout[o];
}

extern "C" void kernel_launch(void* const* d_in, const int* in_sizes, int n_in,
                              void* d_out, int out_size, void* d_ws, size_t ws_size,
                              hipStream_t stream) {
    const int*   x     = (const int*)d_in[0];
    const float* W_ih0 = (const float*)d_in[1];
    const float* W_hh0 = (const float*)d_in[2];
    const float* b_ih0 = (const float*)d_in[3];
    const float* b_hh0 = (const float*)d_in[4];
    const float* W_ih1 = (const float*)d_in[5];
    const float* W_hh1 = (const float*)d_in[6];
    const float* b_ih1 = (const float*)d_in[7];
    const float* b_hh1 = (const float*)d_in[8];
    const float* W_out = (const float*)d_in[9];
    const float* b_out = (const float*)d_in[10];

    // ws: hdr 16KB | h1ring D1*64KB (512KB) | h2ring D2*64KB (128KB) | h2final 128KB
    const size_t needed = (size_t)HDR_INTS * 4 + (size_t)D1 * BHQ * 8
                        + (size_t)D2 * BHQ * 8 + (size_t)BH * 4;  // 802816 B
    if (ws_size < needed) return;  // signature: absmax=0.149 non-NaN => ws short

    int* hdr = (int*)d_ws;
    u64* h1ring = (u64*)((char*)d_ws + (size_t)HDR_INTS * 4);
    u64* h2ring = h1ring + (size_t)D1 * BHQ;
    float* h2final = (float*)(h2ring + (size_t)D2 * BHQ);

    const long ninit = HDR_INTS + (long)D1 * BHQ + (long)D2 * BHQ;  // 86016
    init_kernel<<<(int)((ninit + 255) / 256), 256, 0, stream>>>(hdr, h1ring, h2ring, x);
    rnn_fused<<<2 * NWG, 256, 0, stream>>>(W_hh0, W_ih0, x, b_ih0, b_hh0,
                                           W_hh1, W_ih1, b_ih1, b_hh1,
                                           h1ring, h2ring, h2final, hdr);
    out_kernel<<<dim3(4, BATCH), 256, 0, stream>>>(h2final, W_out, b_out, (float*)d_out);
}